// Round 7
// baseline (284.248 us; speedup 1.0000x reference)
//
#include <hip/hip_runtime.h>
#include <hip/hip_bf16.h>
#include <math.h>

#define CIN 256
#define CH  64
#define CO  47
#define NPAD 102400   // n=100000 rounded up
#define ELLW 48       // ELL width; deg ~ Poisson(16); bench-verified no overflow (guarded)

typedef __attribute__((ext_vector_type(8))) short bf16x8;
typedef __attribute__((ext_vector_type(4))) float f32x4;

__device__ inline short bf16s(float f) {
    union { __hip_bfloat16 h; short s; } u;
    u.h = __float2bfloat16(f);
    return u.s;
}

__device__ inline float bf2f(short u) {
    union { unsigned int i; float f; } v;
    v.i = ((unsigned int)(unsigned short)u) << 16;
    return v.f;
}

// ---------------- ELL build (single sliced scatter pass) ----------------
// Slicing (r5): block b&7 == node-slice -> slice's ell/cnt region stays in ONE
// XCD's L2. r6 lesson: streaming dst/src re-reads (8x51MB) evicted partial ELL
// lines -> WRITE_SIZE 77.5MB (4x writeback). Fix: NONTEMPORAL loads for the
// streams so they don't displace the ELL working set.

#define EDGE_CHUNK 4096

__global__ void zero_i32(int* __restrict__ p, int n) {
    int i = blockIdx.x * blockDim.x + threadIdx.x;
    if (i < n) p[i] = 0;
}

__global__ __launch_bounds__(256) void fill_ell(const int* __restrict__ src,
                                                const int* __restrict__ dst,
                                                int* __restrict__ cnt,
                                                int* __restrict__ ell, int E, int n) {
    int slice = blockIdx.x & 7;
    int chunk = blockIdx.x >> 3;
    int ssz = (n + 7) >> 3;
    int lo = slice * ssz;
    int hi = min(lo + ssz, n);
    int base = chunk * EDGE_CHUNK;
    int end  = min(base + EDGE_CHUNK, E);
    for (int i = base + threadIdx.x; i < end; i += 256) {
        int d = __builtin_nontemporal_load(&dst[i]);
        if (d >= lo && d < hi) {
            int s = __builtin_nontemporal_load(&src[i]);
            int slot = atomicAdd(&cnt[d], 1);
            if (slot < ELLW) ell[(size_t)d * ELLW + slot] = s;
        }
    }
}

__global__ void dinv_k(const int* __restrict__ cnt, float* __restrict__ dinv, int n) {
    int i = blockIdx.x * blockDim.x + threadIdx.x;
    if (i < n) dinv[i] = rsqrtf(1.0f + (float)cnt[i]);  // self-loop included
}

// ---------------- W1 -> bf16 (once; 32KB, L2-resident for gemm1) ----------------

__global__ void w1_to_bf16(const float* __restrict__ W1, unsigned short* __restrict__ w1bf,
                           int total) {
    int i = blockIdx.x * blockDim.x + threadIdx.x;
    if (i < total) w1bf[i] = (unsigned short)bf16s(W1[i]);
}

// ---------------- layer-1 GEMM (MFMA): h1 = x @ W1^T  (bf16 out) ----------------
// r6 lesson: 391 BM=64 blocks -> ~1.5 blocks/CU quantization tail + per-block
// W1 LDS stage/convert. Now: no LDS, no sync. 4 independent waves/block, each
// owns one 16-row tile (grid 1563). B-frags loaded straight from preconverted
// w1bf in L2 (per load instr: 16 rows x 64B contiguous). x read exactly once.

__global__ __launch_bounds__(256) void gemm1_mfma(const float* __restrict__ x,
                                                  const unsigned short* __restrict__ w1bf,
                                                  unsigned short* __restrict__ h1, int n) {
    int t  = threadIdx.x;
    int l  = t & 63;
    int w  = t >> 6;
    int g  = l >> 4;    // k-group 0..3
    int lr = l & 15;    // row (A) / col (B) within 16

    int ntile = (n + 15) >> 4;          // 6250 (n % 16 == 0)
    int tile = blockIdx.x * 4 + w;
    if (tile >= ntile) return;
    int row0 = tile * 16;

    int arow = row0 + lr;
    if (arow >= n) arow = n - 1;        // clamp (no-op for n%16==0); stores guarded
    const float* ga = x + (size_t)arow * CIN + g * 8;

    f32x4 acc[4];
    #pragma unroll
    for (int cb = 0; cb < 4; ++cb) acc[cb] = (f32x4){0.f, 0.f, 0.f, 0.f};

    #pragma unroll
    for (int kk = 0; kk < 8; ++kk) {
        bf16x8 bq[4];
        #pragma unroll
        for (int cb = 0; cb < 4; ++cb)
            bq[cb] = *(const bf16x8*)(w1bf + (size_t)(cb * 16 + lr) * CIN + kk * 32 + g * 8);
        float4 a0 = *(const float4*)(ga + kk * 32);
        float4 a1 = *(const float4*)(ga + kk * 32 + 4);
        bf16x8 af;
        af[0] = bf16s(a0.x); af[1] = bf16s(a0.y); af[2] = bf16s(a0.z); af[3] = bf16s(a0.w);
        af[4] = bf16s(a1.x); af[5] = bf16s(a1.y); af[6] = bf16s(a1.z); af[7] = bf16s(a1.w);
        #pragma unroll
        for (int cb = 0; cb < 4; ++cb)
            acc[cb] = __builtin_amdgcn_mfma_f32_16x16x32_bf16(af, bq[cb], acc[cb], 0, 0, 0);
    }

    #pragma unroll
    for (int cb = 0; cb < 4; ++cb) {
        #pragma unroll
        for (int r = 0; r < 4; ++r) {
            int drow = row0 + g * 4 + r;    // C/D: col=lane&15, row=(lane>>4)*4+reg
            if (drow < n) h1[(size_t)drow * CH + cb * 16 + lr] = (unsigned short)bf16s(acc[cb][r]);
        }
    }
}

// ---------------- layer-2 GEMM (MFMA): h2 = agg1 @ W2^T (bf16 in/out) ----------------

__global__ __launch_bounds__(256) void gemm2_mfma(const unsigned short* __restrict__ agg1,
                                                  const float* __restrict__ W2,
                                                  unsigned short* __restrict__ h2, int n) {
    __shared__ short w2s[48 * CH];   // [48][64] bf16 swizzled, row 47 zeroed (6 KB)
    int t = threadIdx.x;
    int row0 = blockIdx.x * 64;

    for (int i = t; i < 48 * (CH / 4); i += 256) {
        int row = i >> 4;
        int f4  = i & 15;
        float4 v;
        if (row < CO) v = *(const float4*)(W2 + (size_t)row * CH + f4 * 4);
        else          v = make_float4(0.f, 0.f, 0.f, 0.f);
        short b[4];
        b[0] = bf16s(v.x); b[1] = bf16s(v.y); b[2] = bf16s(v.z); b[3] = bf16s(v.w);
        int kbyte = f4 * 8;
        *(long long*)((char*)w2s + (row << 7) + (kbyte ^ ((row & 7) << 4))) = *(long long*)b;
    }
    __syncthreads();

    int l  = t & 63;
    int w  = t >> 6;
    int g  = l >> 4;
    int lr = l & 15;

    bf16x8 bfr[3][2];
    #pragma unroll
    for (int cb = 0; cb < 3; ++cb) {
        int col = cb * 16 + lr;
        #pragma unroll
        for (int kk = 0; kk < 2; ++kk) {
            int kbyte = (kk * 32 + g * 8) * 2;
            bfr[cb][kk] = *(const bf16x8*)((char*)w2s + (col << 7) + (kbyte ^ ((col & 7) << 4)));
        }
    }

    f32x4 acc[3];
    #pragma unroll
    for (int cb = 0; cb < 3; ++cb) acc[cb] = (f32x4){0.f, 0.f, 0.f, 0.f};

    int arow = row0 + w * 16 + lr;
    if (arow >= n) arow = n - 1;
    const unsigned short* ga = agg1 + (size_t)arow * CH + g * 8;

    #pragma unroll
    for (int kk = 0; kk < 2; ++kk) {
        bf16x8 af = *(const bf16x8*)(ga + kk * 32);
        #pragma unroll
        for (int cb = 0; cb < 3; ++cb)
            acc[cb] = __builtin_amdgcn_mfma_f32_16x16x32_bf16(af, bfr[cb][kk], acc[cb], 0, 0, 0);
    }

    #pragma unroll
    for (int cb = 0; cb < 3; ++cb) {
        #pragma unroll
        for (int r = 0; r < 4; ++r) {
            int drow = row0 + w * 16 + g * 4 + r;
            int col  = cb * 16 + lr;
            if (drow < n && col < CO)
                h2[(size_t)drow * 48 + col] = (unsigned short)bf16s(acc[cb][r]);
        }
    }
}

// ---------------- gather aggregation over ELL, 8-edge ILP ----------------
// One wave per node. 8 groups x 8 lanes; group g handles slots g, g+8, ...
// lane r of a group loads 16B (8 bf16 channels) of the source row.
// ell reads are one-shot streams -> nontemporal (protect cached h rows).
// MODE 0: out = bf16 relu(acc+bias)   MODE 1: out = f32 sigmoid(acc+bias)

template <int STRIDE, int COUT, int MODE>
__global__ __launch_bounds__(256) void aggregate(const unsigned short* __restrict__ h,
                                                 const float* __restrict__ dinv,
                                                 const int* __restrict__ ell,
                                                 const int* __restrict__ cnt,
                                                 const float* __restrict__ bias,
                                                 void* __restrict__ out_, int n) {
    constexpr int NL = STRIDE / 8;   // active load-lanes per group (8 for 64, 6 for 48)
    int lane = threadIdx.x & 63;
    int node = blockIdx.x * (blockDim.x >> 6) + (threadIdx.x >> 6);
    if (node >= n) return;
    int g = lane >> 3;
    int r = lane & 7;

    float di = dinv[node];
    int deg = min(cnt[node], ELLW);          // clamp: overflow slots were dropped
    const int* row = ell + (size_t)node * ELLW;

    float acc[8];
    #pragma unroll
    for (int i = 0; i < 8; ++i) acc[i] = 0.f;

    // self-loop term: group 0 only
    if (g == 0 && r < NL) {
        bf16x8 v = *(const bf16x8*)(h + (size_t)node * STRIDE + r * 8);
        float w = di * di;
        #pragma unroll
        for (int i = 0; i < 8; ++i) acc[i] += bf2f(v[i]) * w;
    }

    for (int j = g; j < deg; j += 8) {
        int s = __builtin_nontemporal_load(&row[j]);
        float w = dinv[s] * di;
        if (r < NL) {
            bf16x8 v = *(const bf16x8*)(h + (size_t)s * STRIDE + r * 8);
            #pragma unroll
            for (int i = 0; i < 8; ++i) acc[i] += bf2f(v[i]) * w;
        }
    }

    // reduce the 8 edge-groups: butterfly over lane bits 3,4,5
    #pragma unroll
    for (int m = 8; m <= 32; m <<= 1) {
        #pragma unroll
        for (int i = 0; i < 8; ++i) acc[i] += __shfl_xor(acc[i], m, 64);
    }

    if (g == 0 && r < NL) {
        #pragma unroll
        for (int i = 0; i < 8; ++i) {
            int c = r * 8 + i;
            if (STRIDE == COUT || c < COUT) {
                float v = acc[i] + bias[c];
                if (MODE == 0) {
                    v = fmaxf(v, 0.0f);
                    ((unsigned short*)out_)[(size_t)node * COUT + c] = (unsigned short)bf16s(v);
                } else {
                    v = 1.0f / (1.0f + __expf(-v));
                    ((float*)out_)[(size_t)node * COUT + c] = v;
                }
            }
        }
    }
}

// ---------------- launch ----------------

extern "C" void kernel_launch(void* const* d_in, const int* in_sizes, int n_in,
                              void* d_out, int out_size, void* d_ws, size_t ws_size,
                              hipStream_t stream) {
    const float* x  = (const float*)d_in[0];
    const int*   ei = (const int*)d_in[1];
    const float* W1 = (const float*)d_in[2];
    const float* b1 = (const float*)d_in[3];
    const float* W2 = (const float*)d_in[4];
    const float* b2 = (const float*)d_in[5];
    float* out = (float*)d_out;

    int n = in_sizes[0] / CIN;   // 100000
    int E = in_sizes[1] / 2;     // 1600000
    const int* src = ei;
    const int* dst = ei + E;

    // workspace layout (16B-aligned regions), total ~46.8 MB
    int*   cnt  = (int*)d_ws;                              // NPAD ints      (0.4 MB)
    float* dinv = (float*)(cnt + NPAD);                    // NPAD floats    (0.4 MB)
    int*   ell  = (int*)(dinv + NPAD);                     // NPAD*48 ints   (19.7 MB)
    unsigned short* h1   = (unsigned short*)(ell + (size_t)NPAD * ELLW); // NPAD*64 (13.1 MB)
    unsigned short* agg1 = h1 + (size_t)NPAD * CH;                       // NPAD*64 (13.1 MB)
    unsigned short* w1bf = agg1 + (size_t)NPAD * CH;                     // 16384   (32 KB)
    unsigned short* h2   = h1;   // alias: h1 dead after aggregate1

    int nb_n = (n + 255) / 256;
    int nb_w = (n + 3) / 4;                    // 4 waves/block, 1 node/wave
    int nb_g2 = (n + 63) / 64;                 // gemm2 BM=64 blocks
    int nb_g1 = ((n + 15) / 16 + 3) / 4;       // gemm1: 4 tiles of 16 rows per block
    int nchunks = (E + EDGE_CHUNK - 1) / EDGE_CHUNK;
    int nb_sl = nchunks * 8;                   // sliced grid (slice = blockIdx&7)

    // ELL build (+ dinv) and W1 preconvert
    zero_i32<<<nb_n, 256, 0, stream>>>(cnt, n);
    w1_to_bf16<<<(CH * CIN + 255) / 256, 256, 0, stream>>>(W1, w1bf, CH * CIN);
    fill_ell<<<nb_sl, 256, 0, stream>>>(src, dst, cnt, ell, E, n);
    dinv_k<<<nb_n, 256, 0, stream>>>(cnt, dinv, n);

    // layer 1
    gemm1_mfma<<<nb_g1, 256, 0, stream>>>(x, w1bf, h1, n);
    aggregate<CH, CH, 0><<<nb_w, 256, 0, stream>>>(h1, dinv, ell, cnt, b1, agg1, n);

    // layer 2
    gemm2_mfma<<<nb_g2, 256, 0, stream>>>(agg1, W2, h2, n);
    aggregate<48, CO, 1><<<nb_w, 256, 0, stream>>>(h2, dinv, ell, cnt, b2, out, n);
}

// Round 8
// 268.770 us; speedup vs baseline: 1.0576x; 1.0576x over previous
//
#include <hip/hip_runtime.h>
#include <hip/hip_bf16.h>
#include <math.h>

#define CIN 256
#define CH  64
#define CO  47
#define NPAD 102400   // n=100000 rounded up
#define ELLW 48       // ELL width; deg ~ Poisson(16); overflow guarded
#define EDGE_CHUNK 4096
#define BIN_CAP 212992  // per-slice int2 capacity: E/8=200000 + ~29-sigma slack

typedef __attribute__((ext_vector_type(8))) short bf16x8;
typedef __attribute__((ext_vector_type(4))) short short4v;
typedef __attribute__((ext_vector_type(4))) float f32x4;

__device__ inline short bf16s(float f) {
    union { __hip_bfloat16 h; short s; } u;
    u.h = __float2bfloat16(f);
    return u.s;
}

__device__ inline float bf2f(short u) {
    union { unsigned int i; float f; } v;
    v.i = ((unsigned int)(unsigned short)u) << 16;
    return v.f;
}

// ---------------- two-phase ELL build ----------------
// r6/r7 lesson: single-pass sliced scatter thrashes L2 (WRITE_SIZE 65-77MB for
// 6.5MB payload) because the 8x dst/src streams evict partial ELL lines between
// the ~16 writes each line needs. Phase 1 reads the edge list ONCE and bins
// (d,s) pairs by dst-slice via LDS staging + per-block reservation (coalesced
// append streams out). Phase 2: each slice's blocks (b&7 -> one XCD) read only
// their own contiguous 1.6MB bin and scatter into a fully L2-resident 2.5MB
// ELL region -- no competing streams, lines complete before writeback.

__global__ void zero_i32(int* __restrict__ p, int n) {
    int i = blockIdx.x * blockDim.x + threadIdx.x;
    if (i < n) p[i] = 0;
}

__global__ __launch_bounds__(256) void bin_edges(const int* __restrict__ src,
                                                 const int* __restrict__ dst,
                                                 int* __restrict__ bin_cnt,
                                                 int2* __restrict__ bins,
                                                 int E, float inv8) {
    __shared__ int2 stage[EDGE_CHUNK];   // 32 KB
    __shared__ int lcnt[8], lbase[9], lcur[8], gbase[8];
    int t = threadIdx.x;
    int base = blockIdx.x * EDGE_CHUNK;
    int end = min(base + EDGE_CHUNK, E);
    if (t < 8) lcnt[t] = 0;
    __syncthreads();

    // pass A: per-slice counts (slice via float mul; mis-slice at boundary is
    // harmless -- slice choice affects locality only, never correctness)
    for (int i = base + t; i < end; i += 256) {
        int d = __builtin_nontemporal_load(&dst[i]);
        int sl = min(7, (int)((float)d * inv8));
        atomicAdd(&lcnt[sl], 1);
    }
    __syncthreads();
    if (t == 0) {
        int s = 0;
        #pragma unroll
        for (int k = 0; k < 8; ++k) { lbase[k] = s; lcur[k] = s; s += lcnt[k]; }
        lbase[8] = s;
    }
    __syncthreads();

    // pass B: stage grouped by slice
    for (int i = base + t; i < end; i += 256) {
        int d = __builtin_nontemporal_load(&dst[i]);
        int s = __builtin_nontemporal_load(&src[i]);
        int sl = min(7, (int)((float)d * inv8));
        int pos = atomicAdd(&lcur[sl], 1);
        stage[pos] = make_int2(d, s);
    }
    __syncthreads();

    // reserve global space: ONE atomic per block per slice
    if (t < 8) gbase[t] = atomicAdd(&bin_cnt[t], lcnt[t]);
    __syncthreads();

    // pass C: copy out, coalesced within slice segments
    int total = end - base;
    for (int j = t; j < total; j += 256) {
        int sl = 7;
        #pragma unroll
        for (int k = 6; k >= 0; --k) if (j < lbase[k + 1]) sl = k;
        int pos = gbase[sl] + (j - lbase[sl]);
        if (pos < BIN_CAP) bins[(size_t)sl * BIN_CAP + pos] = stage[j];
    }
}

__global__ __launch_bounds__(256) void fill_ell2(const int2* __restrict__ bins,
                                                 const int* __restrict__ bin_cnt,
                                                 int* __restrict__ cnt,
                                                 int* __restrict__ ell) {
    int slice = blockIdx.x & 7;          // round-robin blockIdx -> XCD (r5-proven)
    int blk   = blockIdx.x >> 3;
    int nblk  = gridDim.x >> 3;
    int c_sl  = min(bin_cnt[slice], BIN_CAP);
    const long long* b = (const long long*)(bins + (size_t)slice * BIN_CAP);
    for (int i = blk * 256 + threadIdx.x; i < c_sl; i += nblk * 256) {
        long long e = __builtin_nontemporal_load(&b[i]);
        int d = (int)(e & 0xffffffffLL);
        int s = (int)(e >> 32);
        int slot = atomicAdd(&cnt[d], 1);
        if (slot < ELLW) ell[(size_t)d * ELLW + slot] = s;
    }
}

__global__ void dinv_k(const int* __restrict__ cnt, float* __restrict__ dinv, int n) {
    int i = blockIdx.x * blockDim.x + threadIdx.x;
    if (i < n) dinv[i] = rsqrtf(1.0f + (float)cnt[i]);  // self-loop included
}

// ---------------- layer-1 GEMM (MFMA): h1 = x @ W1^T  (bf16 out) ----------------
// r6-proven form: W1 staged once/block to LDS (bf16, XOR-swizzled), BM=64.

__global__ __launch_bounds__(256) void gemm1_mfma(const float* __restrict__ x,
                                                  const float* __restrict__ W1,
                                                  unsigned short* __restrict__ h1, int n) {
    __shared__ short w1s[CH * CIN];  // [64][256] bf16, swizzled rows (32 KB)
    int t = threadIdx.x;
    int row0 = blockIdx.x * 64;

    for (int i = t; i < CH * (CIN / 4); i += 256) {
        int row = i >> 6;
        int f4  = i & 63;
        float4 v = *(const float4*)(W1 + (size_t)row * CIN + f4 * 4);
        short4v b;
        b[0] = bf16s(v.x); b[1] = bf16s(v.y); b[2] = bf16s(v.z); b[3] = bf16s(v.w);
        int kbyte = f4 * 8;
        *(short4v*)((char*)w1s + (row << 9) + (kbyte ^ ((row & 7) << 4))) = b;
    }
    __syncthreads();

    int l  = t & 63;
    int w  = t >> 6;
    int g  = l >> 4;
    int lr = l & 15;

    bf16x8 bfr[4][8];
    #pragma unroll
    for (int cb = 0; cb < 4; ++cb) {
        int col = cb * 16 + lr;
        #pragma unroll
        for (int kk = 0; kk < 8; ++kk) {
            int kbyte = (kk * 32 + g * 8) * 2;
            bfr[cb][kk] = *(const bf16x8*)((char*)w1s + (col << 9) + (kbyte ^ ((col & 7) << 4)));
        }
    }

    f32x4 acc[4];
    #pragma unroll
    for (int cb = 0; cb < 4; ++cb) acc[cb] = (f32x4){0.f, 0.f, 0.f, 0.f};

    int arow = row0 + w * 16 + lr;
    if (arow >= n) arow = n - 1;     // clamp: loads stay in-bounds; store guarded
    const float* ga = x + (size_t)arow * CIN + g * 8;

    #pragma unroll
    for (int kk = 0; kk < 8; ++kk) {
        float4 a0 = *(const float4*)(ga + kk * 32);
        float4 a1 = *(const float4*)(ga + kk * 32 + 4);
        bf16x8 af;
        af[0] = bf16s(a0.x); af[1] = bf16s(a0.y); af[2] = bf16s(a0.z); af[3] = bf16s(a0.w);
        af[4] = bf16s(a1.x); af[5] = bf16s(a1.y); af[6] = bf16s(a1.z); af[7] = bf16s(a1.w);
        #pragma unroll
        for (int cb = 0; cb < 4; ++cb)
            acc[cb] = __builtin_amdgcn_mfma_f32_16x16x32_bf16(af, bfr[cb][kk], acc[cb], 0, 0, 0);
    }

    #pragma unroll
    for (int cb = 0; cb < 4; ++cb) {
        #pragma unroll
        for (int r = 0; r < 4; ++r) {
            int drow = row0 + w * 16 + g * 4 + r;   // C/D: col=lane&15, row=(lane>>4)*4+reg
            if (drow < n) h1[(size_t)drow * CH + cb * 16 + lr] = (unsigned short)bf16s(acc[cb][r]);
        }
    }
}

// ---------------- layer-2 GEMM (MFMA): h2 = agg1 @ W2^T (bf16 in/out) ----------------

__global__ __launch_bounds__(256) void gemm2_mfma(const unsigned short* __restrict__ agg1,
                                                  const float* __restrict__ W2,
                                                  unsigned short* __restrict__ h2, int n) {
    __shared__ short w2s[48 * CH];   // [48][64] bf16 swizzled, row 47 zeroed (6 KB)
    int t = threadIdx.x;
    int row0 = blockIdx.x * 64;

    for (int i = t; i < 48 * (CH / 4); i += 256) {
        int row = i >> 4;
        int f4  = i & 15;
        float4 v;
        if (row < CO) v = *(const float4*)(W2 + (size_t)row * CH + f4 * 4);
        else          v = make_float4(0.f, 0.f, 0.f, 0.f);
        short4v b;
        b[0] = bf16s(v.x); b[1] = bf16s(v.y); b[2] = bf16s(v.z); b[3] = bf16s(v.w);
        int kbyte = f4 * 8;
        *(short4v*)((char*)w2s + (row << 7) + (kbyte ^ ((row & 7) << 4))) = b;
    }
    __syncthreads();

    int l  = t & 63;
    int w  = t >> 6;
    int g  = l >> 4;
    int lr = l & 15;

    bf16x8 bfr[3][2];
    #pragma unroll
    for (int cb = 0; cb < 3; ++cb) {
        int col = cb * 16 + lr;
        #pragma unroll
        for (int kk = 0; kk < 2; ++kk) {
            int kbyte = (kk * 32 + g * 8) * 2;
            bfr[cb][kk] = *(const bf16x8*)((char*)w2s + (col << 7) + (kbyte ^ ((col & 7) << 4)));
        }
    }

    f32x4 acc[3];
    #pragma unroll
    for (int cb = 0; cb < 3; ++cb) acc[cb] = (f32x4){0.f, 0.f, 0.f, 0.f};

    int arow = row0 + w * 16 + lr;
    if (arow >= n) arow = n - 1;
    const unsigned short* ga = agg1 + (size_t)arow * CH + g * 8;

    #pragma unroll
    for (int kk = 0; kk < 2; ++kk) {
        bf16x8 af = *(const bf16x8*)(ga + kk * 32);
        #pragma unroll
        for (int cb = 0; cb < 3; ++cb)
            acc[cb] = __builtin_amdgcn_mfma_f32_16x16x32_bf16(af, bfr[cb][kk], acc[cb], 0, 0, 0);
    }

    #pragma unroll
    for (int cb = 0; cb < 3; ++cb) {
        #pragma unroll
        for (int r = 0; r < 4; ++r) {
            int drow = row0 + w * 16 + g * 4 + r;
            int col  = cb * 16 + lr;
            if (drow < n && col < CO)
                h2[(size_t)drow * 48 + col] = (unsigned short)bf16s(acc[cb][r]);
        }
    }
}

// ---------------- gather aggregation over ELL, 8-edge ILP (r6-proven) ----------------

template <int STRIDE, int COUT, int MODE>
__global__ __launch_bounds__(256) void aggregate(const unsigned short* __restrict__ h,
                                                 const float* __restrict__ dinv,
                                                 const int* __restrict__ ell,
                                                 const int* __restrict__ cnt,
                                                 const float* __restrict__ bias,
                                                 void* __restrict__ out_, int n) {
    constexpr int NL = STRIDE / 8;   // active load-lanes per group (8 for 64, 6 for 48)
    int lane = threadIdx.x & 63;
    int node = blockIdx.x * (blockDim.x >> 6) + (threadIdx.x >> 6);
    if (node >= n) return;
    int g = lane >> 3;
    int r = lane & 7;

    float di = dinv[node];
    int deg = min(cnt[node], ELLW);          // clamp: overflow slots were dropped
    const int* row = ell + (size_t)node * ELLW;

    float acc[8];
    #pragma unroll
    for (int i = 0; i < 8; ++i) acc[i] = 0.f;

    if (g == 0 && r < NL) {                  // self-loop term
        bf16x8 v = *(const bf16x8*)(h + (size_t)node * STRIDE + r * 8);
        float w = di * di;
        #pragma unroll
        for (int i = 0; i < 8; ++i) acc[i] += bf2f(v[i]) * w;
    }

    for (int j = g; j < deg; j += 8) {
        int s = row[j];
        float w = dinv[s] * di;
        if (r < NL) {
            bf16x8 v = *(const bf16x8*)(h + (size_t)s * STRIDE + r * 8);
            #pragma unroll
            for (int i = 0; i < 8; ++i) acc[i] += bf2f(v[i]) * w;
        }
    }

    #pragma unroll
    for (int m = 8; m <= 32; m <<= 1) {
        #pragma unroll
        for (int i = 0; i < 8; ++i) acc[i] += __shfl_xor(acc[i], m, 64);
    }

    if (g == 0 && r < NL) {
        #pragma unroll
        for (int i = 0; i < 8; ++i) {
            int c = r * 8 + i;
            if (STRIDE == COUT || c < COUT) {
                float v = acc[i] + bias[c];
                if (MODE == 0) {
                    v = fmaxf(v, 0.0f);
                    ((unsigned short*)out_)[(size_t)node * COUT + c] = (unsigned short)bf16s(v);
                } else {
                    v = 1.0f / (1.0f + __expf(-v));
                    ((float*)out_)[(size_t)node * COUT + c] = v;
                }
            }
        }
    }
}

// ---------------- launch ----------------

extern "C" void kernel_launch(void* const* d_in, const int* in_sizes, int n_in,
                              void* d_out, int out_size, void* d_ws, size_t ws_size,
                              hipStream_t stream) {
    const float* x  = (const float*)d_in[0];
    const int*   ei = (const int*)d_in[1];
    const float* W1 = (const float*)d_in[2];
    const float* b1 = (const float*)d_in[3];
    const float* W2 = (const float*)d_in[4];
    const float* b2 = (const float*)d_in[5];
    float* out = (float*)d_out;

    int n = in_sizes[0] / CIN;   // 100000
    int E = in_sizes[1] / 2;     // 1600000
    const int* src = ei;
    const int* dst = ei + E;

    // workspace layout (16B-aligned regions), total ~46.8 MB
    int*   cnt     = (int*)d_ws;                           // NPAD ints      (0.4 MB)
    float* dinv    = (float*)(cnt + NPAD);                 // NPAD floats    (0.4 MB)
    int*   bin_cnt = (int*)(dinv + NPAD);                  // 16 ints
    int*   ell     = bin_cnt + 16;                         // NPAD*48 ints   (19.7 MB)
    unsigned short* h1   = (unsigned short*)(ell + (size_t)NPAD * ELLW); // NPAD*64 (13.1 MB)
    unsigned short* agg1 = h1 + (size_t)NPAD * CH;                       // NPAD*64 (13.1 MB)
    unsigned short* h2   = h1;               // alias: h1 dead after aggregate1
    int2* bins = (int2*)h1;                  // alias: bins (13.6 MB over h1 + head of agg1)
                                             // dead before gemm1 writes h1 (stream-serialized)

    int nb_n = (n + 255) / 256;
    int nb_w = (n + 3) / 4;                    // 4 waves/block, 1 node/wave
    int nb_g = (n + 63) / 64;
    int nchunks = (E + EDGE_CHUNK - 1) / EDGE_CHUNK;

    // ELL build: bin once, scatter within-XCD
    zero_i32<<<nb_n, 256, 0, stream>>>(cnt, n);
    zero_i32<<<1, 256, 0, stream>>>(bin_cnt, 16);
    bin_edges<<<nchunks, 256, 0, stream>>>(src, dst, bin_cnt, bins, E, 8.0f / (float)n);
    fill_ell2<<<512, 256, 0, stream>>>(bins, bin_cnt, cnt, ell);
    dinv_k<<<nb_n, 256, 0, stream>>>(cnt, dinv, n);

    // layer 1
    gemm1_mfma<<<nb_g, 256, 0, stream>>>(x, W1, h1, n);
    aggregate<CH, CH, 0><<<nb_w, 256, 0, stream>>>(h1, dinv, ell, cnt, b1, agg1, n);

    // layer 2
    gemm2_mfma<<<nb_g, 256, 0, stream>>>(agg1, W2, h2, n);
    aggregate<48, CO, 1><<<nb_w, 256, 0, stream>>>(h2, dinv, ell, cnt, b2, out, n);
}

// Round 9
// 245.521 us; speedup vs baseline: 1.1577x; 1.0947x over previous
//
#include <hip/hip_runtime.h>
#include <hip/hip_bf16.h>
#include <math.h>

#define CIN 256
#define CH  64
#define CO  47
#define NPAD 102400   // n=100000 rounded up
#define ELLW 48       // ELL width; deg ~ Poisson(16); overflow guarded
#define EDGE_CHUNK 4096
#define BIN_CAP 212992  // per-slice int2 capacity: E/8=200000 + slack

typedef __attribute__((ext_vector_type(8))) short bf16x8;
typedef __attribute__((ext_vector_type(4))) short short4v;
typedef __attribute__((ext_vector_type(4))) float f32x4;

__device__ inline short bf16s(float f) {
    union { __hip_bfloat16 h; short s; } u;
    u.h = __float2bfloat16(f);
    return u.s;
}

__device__ inline float bf2f(short u) {
    union { unsigned int i; float f; } v;
    v.i = ((unsigned int)(unsigned short)u) << 16;
    return v.f;
}

// ---------------- two-phase ELL build (r8-proven, frozen) ----------------

__global__ void zero_i32(int* __restrict__ p, int n) {
    int i = blockIdx.x * blockDim.x + threadIdx.x;
    if (i < n) p[i] = 0;
}

__global__ __launch_bounds__(256) void bin_edges(const int* __restrict__ src,
                                                 const int* __restrict__ dst,
                                                 int* __restrict__ bin_cnt,
                                                 int2* __restrict__ bins,
                                                 int E, float inv8) {
    __shared__ int2 stage[EDGE_CHUNK];   // 32 KB
    __shared__ int lcnt[8], lbase[9], lcur[8], gbase[8];
    int t = threadIdx.x;
    int base = blockIdx.x * EDGE_CHUNK;
    int end = min(base + EDGE_CHUNK, E);
    if (t < 8) lcnt[t] = 0;
    __syncthreads();

    for (int i = base + t; i < end; i += 256) {
        int d = __builtin_nontemporal_load(&dst[i]);
        int sl = min(7, (int)((float)d * inv8));
        atomicAdd(&lcnt[sl], 1);
    }
    __syncthreads();
    if (t == 0) {
        int s = 0;
        #pragma unroll
        for (int k = 0; k < 8; ++k) { lbase[k] = s; lcur[k] = s; s += lcnt[k]; }
        lbase[8] = s;
    }
    __syncthreads();

    for (int i = base + t; i < end; i += 256) {
        int d = __builtin_nontemporal_load(&dst[i]);
        int s = __builtin_nontemporal_load(&src[i]);
        int sl = min(7, (int)((float)d * inv8));
        int pos = atomicAdd(&lcur[sl], 1);
        stage[pos] = make_int2(d, s);
    }
    __syncthreads();

    if (t < 8) gbase[t] = atomicAdd(&bin_cnt[t], lcnt[t]);
    __syncthreads();

    int total = end - base;
    for (int j = t; j < total; j += 256) {
        int sl = 7;
        #pragma unroll
        for (int k = 6; k >= 0; --k) if (j < lbase[k + 1]) sl = k;
        int pos = gbase[sl] + (j - lbase[sl]);
        if (pos < BIN_CAP) bins[(size_t)sl * BIN_CAP + pos] = stage[j];
    }
}

__global__ __launch_bounds__(256) void fill_ell2(const int2* __restrict__ bins,
                                                 const int* __restrict__ bin_cnt,
                                                 int* __restrict__ cnt,
                                                 int* __restrict__ ell) {
    int slice = blockIdx.x & 7;          // round-robin blockIdx -> XCD
    int blk   = blockIdx.x >> 3;
    int nblk  = gridDim.x >> 3;
    int c_sl  = min(bin_cnt[slice], BIN_CAP);
    const long long* b = (const long long*)(bins + (size_t)slice * BIN_CAP);
    for (int i = blk * 256 + threadIdx.x; i < c_sl; i += nblk * 256) {
        long long e = __builtin_nontemporal_load(&b[i]);
        int d = (int)(e & 0xffffffffLL);
        int s = (int)(e >> 32);
        int slot = atomicAdd(&cnt[d], 1);
        if (slot < ELLW) ell[(size_t)d * ELLW + slot] = s;
    }
}

__global__ void dinv_k(const int* __restrict__ cnt, float* __restrict__ dinv, int n) {
    int i = blockIdx.x * blockDim.x + threadIdx.x;
    if (i < n) dinv[i] = rsqrtf(1.0f + (float)cnt[i]);  // self-loop included
}

// ---------------- layer-1 GEMM (MFMA): h1p = dinv * (x @ W1^T)  (bf16 out) ----------------
// Premultiplied by dinv[row] so aggregation is pure adds (norm factorization:
// out = di * (sum_nbr h1p[s] + h1p[node])). r6-proven LDS staging.

__global__ __launch_bounds__(256) void gemm1_mfma(const float* __restrict__ x,
                                                  const float* __restrict__ W1,
                                                  const float* __restrict__ dinv,
                                                  unsigned short* __restrict__ h1p, int n) {
    __shared__ short w1s[CH * CIN];  // [64][256] bf16, swizzled rows (32 KB)
    int t = threadIdx.x;
    int row0 = blockIdx.x * 64;

    for (int i = t; i < CH * (CIN / 4); i += 256) {
        int row = i >> 6;
        int f4  = i & 63;
        float4 v = *(const float4*)(W1 + (size_t)row * CIN + f4 * 4);
        short4v b;
        b[0] = bf16s(v.x); b[1] = bf16s(v.y); b[2] = bf16s(v.z); b[3] = bf16s(v.w);
        int kbyte = f4 * 8;
        *(short4v*)((char*)w1s + (row << 9) + (kbyte ^ ((row & 7) << 4))) = b;
    }
    __syncthreads();

    int l  = t & 63;
    int w  = t >> 6;
    int g  = l >> 4;
    int lr = l & 15;

    bf16x8 bfr[4][8];
    #pragma unroll
    for (int cb = 0; cb < 4; ++cb) {
        int col = cb * 16 + lr;
        #pragma unroll
        for (int kk = 0; kk < 8; ++kk) {
            int kbyte = (kk * 32 + g * 8) * 2;
            bfr[cb][kk] = *(const bf16x8*)((char*)w1s + (col << 9) + (kbyte ^ ((col & 7) << 4)));
        }
    }

    f32x4 acc[4];
    #pragma unroll
    for (int cb = 0; cb < 4; ++cb) acc[cb] = (f32x4){0.f, 0.f, 0.f, 0.f};

    int arow = row0 + w * 16 + lr;
    if (arow >= n) arow = n - 1;     // clamp: loads stay in-bounds; store guarded
    const float* ga = x + (size_t)arow * CIN + g * 8;

    #pragma unroll
    for (int kk = 0; kk < 8; ++kk) {
        float4 a0 = *(const float4*)(ga + kk * 32);
        float4 a1 = *(const float4*)(ga + kk * 32 + 4);
        bf16x8 af;
        af[0] = bf16s(a0.x); af[1] = bf16s(a0.y); af[2] = bf16s(a0.z); af[3] = bf16s(a0.w);
        af[4] = bf16s(a1.x); af[5] = bf16s(a1.y); af[6] = bf16s(a1.z); af[7] = bf16s(a1.w);
        #pragma unroll
        for (int cb = 0; cb < 4; ++cb)
            acc[cb] = __builtin_amdgcn_mfma_f32_16x16x32_bf16(af, bfr[cb][kk], acc[cb], 0, 0, 0);
    }

    // epilogue: premultiply by dinv[drow]
    float dv[4];
    #pragma unroll
    for (int r = 0; r < 4; ++r) {
        int drow = row0 + w * 16 + g * 4 + r;
        dv[r] = dinv[drow < n ? drow : (n - 1)];
    }
    #pragma unroll
    for (int cb = 0; cb < 4; ++cb) {
        #pragma unroll
        for (int r = 0; r < 4; ++r) {
            int drow = row0 + w * 16 + g * 4 + r;   // C/D: col=lane&15, row=(lane>>4)*4+reg
            if (drow < n)
                h1p[(size_t)drow * CH + cb * 16 + lr] = (unsigned short)bf16s(acc[cb][r] * dv[r]);
        }
    }
}

// ---------------- gather aggregation over ELL: pure adds, 8-edge groups, x2 unroll ----
// One wave per node. 8 groups x 8 lanes; group g handles slots g, g+8, ...,
// two slots per iteration (16 independent 16B row loads in flight per wave).
// lane r of a group owns channels r*8..r*8+7 (16B of the row).
// MODE 0 (layer 1): out = bf16( di * relu(di*acc + b1) )   [premult for layer 2]
// MODE 1 (layer 2): out = bf16( di * acc )                  [input to final gemm]

template <int MODE>
__global__ __launch_bounds__(256) void aggregate(const unsigned short* __restrict__ h,
                                                 const float* __restrict__ dinv,
                                                 const int* __restrict__ ell,
                                                 const int* __restrict__ cnt,
                                                 const float* __restrict__ bias,
                                                 unsigned short* __restrict__ outp, int n) {
    int lane = threadIdx.x & 63;
    int node = blockIdx.x * (blockDim.x >> 6) + (threadIdx.x >> 6);
    if (node >= n) return;
    int g = lane >> 3;
    int r = lane & 7;

    float di = dinv[node];
    int deg = min(cnt[node], ELLW);          // clamp: overflow slots were dropped
    const int* row = ell + (size_t)node * ELLW;

    float acc[8];
    #pragma unroll
    for (int i = 0; i < 8; ++i) acc[i] = 0.f;

    if (g == 0) {                            // self term: h_p[node], weight 1
        bf16x8 v = *(const bf16x8*)(h + (size_t)node * CH + r * 8);
        #pragma unroll
        for (int i = 0; i < 8; ++i) acc[i] += bf2f(v[i]);
    }

    int j = g;
    for (; j + 8 < deg; j += 16) {           // x2 unroll: 2 rows in flight per lane
        int s0 = row[j];
        int s1 = row[j + 8];
        bf16x8 v0 = *(const bf16x8*)(h + (size_t)s0 * CH + r * 8);
        bf16x8 v1 = *(const bf16x8*)(h + (size_t)s1 * CH + r * 8);
        #pragma unroll
        for (int i = 0; i < 8; ++i) acc[i] += bf2f(v0[i]) + bf2f(v1[i]);
    }
    if (j < deg) {
        int s = row[j];
        bf16x8 v = *(const bf16x8*)(h + (size_t)s * CH + r * 8);
        #pragma unroll
        for (int i = 0; i < 8; ++i) acc[i] += bf2f(v[i]);
    }

    #pragma unroll
    for (int m = 8; m <= 32; m <<= 1) {
        #pragma unroll
        for (int i = 0; i < 8; ++i) acc[i] += __shfl_xor(acc[i], m, 64);
    }

    if (g == 0) {
        #pragma unroll
        for (int i = 0; i < 8; ++i) {
            float v = acc[i] * di;           // deferred destination norm
            if (MODE == 0) v = di * fmaxf(v + bias[r * 8 + i], 0.0f);
            outp[(size_t)node * CH + r * 8 + i] = (unsigned short)bf16s(v);
        }
    }
}

// ---------------- final GEMM (MFMA): out = sigmoid(t @ W2^T + b2), fp32 ----------------
// Aggregation moved BEFORE the W2 gemm (linearity), so this writes d_out directly.

__global__ __launch_bounds__(256) void final_gemm(const unsigned short* __restrict__ t_,
                                                  const float* __restrict__ W2,
                                                  const float* __restrict__ b2,
                                                  float* __restrict__ out, int n) {
    __shared__ short w2s[48 * CH];   // [48][64] bf16 swizzled, row 47 zeroed (6 KB)
    int t = threadIdx.x;
    int row0 = blockIdx.x * 64;

    for (int i = t; i < 48 * (CH / 4); i += 256) {
        int row = i >> 4;
        int f4  = i & 15;
        float4 v;
        if (row < CO) v = *(const float4*)(W2 + (size_t)row * CH + f4 * 4);
        else          v = make_float4(0.f, 0.f, 0.f, 0.f);
        short4v b;
        b[0] = bf16s(v.x); b[1] = bf16s(v.y); b[2] = bf16s(v.z); b[3] = bf16s(v.w);
        int kbyte = f4 * 8;
        *(short4v*)((char*)w2s + (row << 7) + (kbyte ^ ((row & 7) << 4))) = b;
    }
    __syncthreads();

    int l  = t & 63;
    int w  = t >> 6;
    int g  = l >> 4;
    int lr = l & 15;

    bf16x8 bfr[3][2];
    #pragma unroll
    for (int cb = 0; cb < 3; ++cb) {
        int col = cb * 16 + lr;
        #pragma unroll
        for (int kk = 0; kk < 2; ++kk) {
            int kbyte = (kk * 32 + g * 8) * 2;
            bfr[cb][kk] = *(const bf16x8*)((char*)w2s + (col << 7) + (kbyte ^ ((col & 7) << 4)));
        }
    }

    f32x4 acc[3];
    #pragma unroll
    for (int cb = 0; cb < 3; ++cb) acc[cb] = (f32x4){0.f, 0.f, 0.f, 0.f};

    int arow = row0 + w * 16 + lr;
    if (arow >= n) arow = n - 1;
    const unsigned short* ga = t_ + (size_t)arow * CH + g * 8;

    #pragma unroll
    for (int kk = 0; kk < 2; ++kk) {
        bf16x8 af = *(const bf16x8*)(ga + kk * 32);
        #pragma unroll
        for (int cb = 0; cb < 3; ++cb)
            acc[cb] = __builtin_amdgcn_mfma_f32_16x16x32_bf16(af, bfr[cb][kk], acc[cb], 0, 0, 0);
    }

    #pragma unroll
    for (int cb = 0; cb < 3; ++cb) {
        #pragma unroll
        for (int r = 0; r < 4; ++r) {
            int drow = row0 + w * 16 + g * 4 + r;
            int col  = cb * 16 + lr;
            if (drow < n && col < CO) {
                float v = acc[cb][r] + b2[col];
                out[(size_t)drow * CO + col] = 1.0f / (1.0f + __expf(-v));
            }
        }
    }
}

// ---------------- launch ----------------

extern "C" void kernel_launch(void* const* d_in, const int* in_sizes, int n_in,
                              void* d_out, int out_size, void* d_ws, size_t ws_size,
                              hipStream_t stream) {
    const float* x  = (const float*)d_in[0];
    const int*   ei = (const int*)d_in[1];
    const float* W1 = (const float*)d_in[2];
    const float* b1 = (const float*)d_in[3];
    const float* W2 = (const float*)d_in[4];
    const float* b2 = (const float*)d_in[5];
    float* out = (float*)d_out;

    int n = in_sizes[0] / CIN;   // 100000
    int E = in_sizes[1] / 2;     // 1600000
    const int* src = ei;
    const int* dst = ei + E;

    // workspace layout (16B-aligned regions), total ~46.8 MB
    int*   cnt     = (int*)d_ws;                           // NPAD ints      (0.4 MB)
    float* dinv    = (float*)(cnt + NPAD);                 // NPAD floats    (0.4 MB)
    int*   bin_cnt = (int*)(dinv + NPAD);                  // 16 ints
    int*   ell     = bin_cnt + 16;                         // NPAD*48 ints   (19.7 MB)
    unsigned short* h1p   = (unsigned short*)(ell + (size_t)NPAD * ELLW); // NPAD*64 (13.1 MB)
    unsigned short* agg1p = h1p + (size_t)NPAD * CH;                      // NPAD*64 (13.1 MB)
    unsigned short* tbuf  = h1p;             // alias: h1p dead after aggregate<0>
    int2* bins = (int2*)h1p;                 // alias: bins dead before gemm1 writes h1p

    int nb_n = (n + 255) / 256;
    int nb_w = (n + 3) / 4;                    // 4 waves/block, 1 node/wave
    int nb_g = (n + 63) / 64;
    int nchunks = (E + EDGE_CHUNK - 1) / EDGE_CHUNK;

    // ELL build: bin once, scatter within-XCD (r8-proven)
    zero_i32<<<nb_n, 256, 0, stream>>>(cnt, n);
    zero_i32<<<1, 256, 0, stream>>>(bin_cnt, 16);
    bin_edges<<<nchunks, 256, 0, stream>>>(src, dst, bin_cnt, bins, E, 8.0f / (float)n);
    fill_ell2<<<512, 256, 0, stream>>>(bins, bin_cnt, cnt, ell);
    dinv_k<<<nb_n, 256, 0, stream>>>(cnt, dinv, n);

    // layer 1: premultiplied gemm -> pure-add aggregate (relu+b1+premult fused)
    gemm1_mfma<<<nb_g, 256, 0, stream>>>(x, W1, dinv, h1p, n);
    aggregate<0><<<nb_w, 256, 0, stream>>>(h1p, dinv, ell, cnt, b1, agg1p, n);

    // layer 2: aggregate first (linearity), then W2 gemm fused with b2+sigmoid
    aggregate<1><<<nb_w, 256, 0, stream>>>(agg1p, dinv, ell, cnt, nullptr, tbuf, n);
    final_gemm<<<nb_g, 256, 0, stream>>>(tbuf, W2, b2, out, n);
}